// Round 9
// baseline (207.565 us; speedup 1.0000x reference)
//
#include <hip/hip_runtime.h>
#include <stdint.h>

#define NB 4      // batch
#define SEQ 1024  // sequence
#define DM 256    // d_model == head_dim
#define NH 8      // heads

typedef __attribute__((ext_vector_type(8))) short bf8;   // 8 bf16 (4 VGPRs)
typedef __attribute__((ext_vector_type(4))) float f4;    // MFMA accumulator

__device__ __forceinline__ unsigned short f2bf(float f) {
  union { float f; uint32_t u; } c; c.f = f;
  uint32_t u = c.u;
  return (unsigned short)((u + 0x7FFFu + ((u >> 16) & 1u)) >> 16); // RNE
}

// async global->LDS DMA, 16B per lane (m97 recipe).
__device__ __forceinline__ void gl_lds16(const unsigned short* g, short* l) {
  __builtin_amdgcn_global_load_lds(
      (const __attribute__((address_space(1))) unsigned int*)g,
      (__attribute__((address_space(3))) unsigned int*)l, 16, 0, 0);
}

// Fragment-major layouts (per bh slice = 262144 elems = 512 KB):
//  q_frag/k_frag: [tile16 (token/16)][dchunk (d/32)][lane64][j8]
//     element (tok = tile*16 + (lane&15), d = dchunk*32 + (lane>>4)*8 + j)
//  v_frag:        [dtile (d/16)][kvchunk (kv/32)][lane64][j8]
//     element (d = dtile*16 + (lane&15), kv = kvchunk*32 + (lane>>4)*8 + j)
// A wave fragment load = lane*8 within one 512-elem block: 1KB fully coalesced.

// ---------------------------------------------------------------------------
// Kernel 0: ALL prep in one launch.  grid (1024, 7), 256 thr.
// z 0..2: transpose Wq/Wk/Wv 256x2048 -> Wt3[z]; z==3: Wo -> WoT;
// z 4..6: convert Q/K/V fp32 -> bf16 Xbf[z-4]
// ---------------------------------------------------------------------------
__global__ __launch_bounds__(256) void prep_kernel(
    const float* __restrict__ Wq, const float* __restrict__ Wk,
    const float* __restrict__ Wv, const float* __restrict__ Wo,
    const float* __restrict__ Q, const float* __restrict__ K,
    const float* __restrict__ V,
    unsigned short* __restrict__ Wt3, unsigned short* __restrict__ WoT,
    unsigned short* __restrict__ Xbf) {
  const int z = blockIdx.y;
  const int tid = threadIdx.x;
  if (z >= 4) {
    const float* src = (z == 4) ? Q : (z == 5) ? K : V;
    const size_t off = (size_t)blockIdx.x * 1024 + tid * 4;
    const float4 v = *(const float4*)(src + off);
    short4 s;
    s.x = (short)f2bf(v.x); s.y = (short)f2bf(v.y);
    s.z = (short)f2bf(v.z); s.w = (short)f2bf(v.w);
    *(short4*)(Xbf + (size_t)(z - 4) * 4096 * 256 + off) = s;
    return;
  }
  if (blockIdx.x >= 512) return;
  const float* in;
  unsigned short* out;
  int R, C, bx, by;
  if (z < 3) {
    in = (z == 0) ? Wq : (z == 1) ? Wk : Wv;
    out = Wt3 + (size_t)z * 2048 * 256;
    R = 256; C = 2048; bx = blockIdx.x & 63; by = blockIdx.x >> 6;
  } else {
    in = Wo; out = WoT;
    R = 2048; C = 256; bx = blockIdx.x & 7; by = blockIdx.x >> 3;
  }
  __shared__ float t[32][33];
  const int c0 = bx * 32, r0 = by * 32;
  const int tx = tid & 31, ty = tid >> 5;
#pragma unroll
  for (int i = 0; i < 4; i++) {
    int r = r0 + ty + i * 8;
    t[ty + i * 8][tx] = in[(size_t)r * C + c0 + tx];
  }
  __syncthreads();
#pragma unroll
  for (int i = 0; i < 4; i++) {
    int c = c0 + ty + i * 8;
    out[(size_t)c * R + r0 + tx] = f2bf(t[tx][ty + i * 8]);
  }
}

// ---------------------------------------------------------------------------
// Kernel 1: QKV projection GEMM, m97-style body; epilogue writes
// FRAGMENT-MAJOR q_frag / k_frag / v_frag (see layouts above) so the
// attention kernel's global fragment loads are fully coalesced.
// ---------------------------------------------------------------------------
__global__ __launch_bounds__(256) void proj_kernel(
    const unsigned short* __restrict__ Xbf, const unsigned short* __restrict__ Wt3,
    const float* __restrict__ bq, const float* __restrict__ bk, const float* __restrict__ bv,
    unsigned short* __restrict__ q_frag, unsigned short* __restrict__ k_frag,
    unsigned short* __restrict__ v_frag) {
  const int z = blockIdx.z;
  const unsigned short* X = Xbf + (size_t)z * 4096 * 256;
  const unsigned short* Wt = Wt3 + (size_t)z * 2048 * 256;
  const float* bias = (z == 0) ? bq : (z == 1) ? bk : bv;

  __shared__ short a_lds[128 * 32];
  __shared__ short b_lds[128 * 32];

  const int tid = threadIdx.x;
  const int wid = tid >> 6, lane = tid & 63;
  const int quad = lane >> 4, l16 = lane & 15;
  const int wm = wid >> 1, wn = wid & 1;
  const int m0 = blockIdx.x * 128, n0 = blockIdx.y * 128;

  f4 acc[4][4];
  const f4 z4 = {0.f, 0.f, 0.f, 0.f};
#pragma unroll
  for (int i = 0; i < 4; i++)
#pragma unroll
    for (int j = 0; j < 4; j++) acc[i][j] = z4;

  const int srow = lane >> 2;
  const int schunk = lane & 3;
  const int cxor = quad ^ (l16 & 3);

  for (int ko = 0; ko < 8; ko++) {
    const int k0 = ko * 32;
#pragma unroll
    for (int j = 0; j < 2; j++) {
      const int i = wid * 2 + j;
      const int row = i * 16 + srow;
      const int sc = (schunk ^ (row & 3)) * 8;
      gl_lds16(X + (size_t)(m0 + row) * DM + k0 + sc, a_lds + i * 512);
      gl_lds16(Wt + (size_t)(n0 + row) * DM + k0 + sc, b_lds + i * 512);
    }
    __syncthreads();
    bf8 af[4], bfv[4];
#pragma unroll
    for (int mi = 0; mi < 4; mi++)
      af[mi] = *(const bf8*)(a_lds + (wm * 64 + mi * 16 + l16) * 32 + cxor * 8);
#pragma unroll
    for (int ni = 0; ni < 4; ni++)
      bfv[ni] = *(const bf8*)(b_lds + (wn * 64 + ni * 16 + l16) * 32 + cxor * 8);
#pragma unroll
    for (int mi = 0; mi < 4; mi++)
#pragma unroll
      for (int ni = 0; ni < 4; ni++)
        acc[mi][ni] = __builtin_amdgcn_mfma_f32_16x16x32_bf16(af[mi], bfv[ni], acc[mi][ni], 0, 0, 0);
    __syncthreads();
  }

  if (z < 2) {
    // q_frag / k_frag: idx = ((bh*64 + tok/16)*8 + d/32)*512
    //                        + ((tok&15) + 16*((d>>3)&3))*8 + (d&7)
    const float scale = (z == 0) ? 0.0625f : 1.0f;  // fold 1/sqrt(256) into q
    unsigned short* dst = (z == 0) ? q_frag : k_frag;
#pragma unroll
    for (int ni = 0; ni < 4; ni++) {
      const int n = n0 + wn * 64 + ni * 16 + l16;
      const float bsv = bias[n];
      const int h = n >> 8, d = n & 255;
      const int dpart = (d >> 5) * 512 + (16 * ((d >> 3) & 3)) * 8 + (d & 7);
#pragma unroll
      for (int mi = 0; mi < 4; mi++) {
#pragma unroll
        for (int reg = 0; reg < 4; reg++) {
          const int m = m0 + wm * 64 + mi * 16 + quad * 4 + reg;
          const int b = m >> 10, sr = m & 1023;
          const size_t idx = ((size_t)(b * NH + h) * 64 + (sr >> 4)) * 4096 +
                             dpart + (sr & 15) * 8;
          dst[idx] = f2bf((acc[mi][ni][reg] + bsv) * scale);
        }
      }
    }
  } else {
    // v_frag: idx = ((bh*16 + d/16)*32 + kv/32)*512
    //               + ((d&15) + 16*((kv>>3)&3))*8 + (kv&7);  4 regs = short4
#pragma unroll
    for (int ni = 0; ni < 4; ni++) {
      const int n = n0 + wn * 64 + ni * 16 + l16;
      const float bsv = bias[n];
      const int h = n >> 8, d = n & 255;
#pragma unroll
      for (int mi = 0; mi < 4; mi++) {
        const int m = m0 + wm * 64 + mi * 16 + quad * 4;
        const int b = m >> 10, sr = m & 1023;
        const size_t idx = ((size_t)(b * NH + h) * 16 + (d >> 4)) * 16384 +
                           (size_t)(sr >> 5) * 512 +
                           ((d & 15) + 16 * ((sr >> 3) & 3)) * 8 + (sr & 7);
        short4 s4;
        s4.x = (short)f2bf(acc[mi][ni][0] + bsv);
        s4.y = (short)f2bf(acc[mi][ni][1] + bsv);
        s4.z = (short)f2bf(acc[mi][ni][2] + bsv);
        s4.w = (short)f2bf(acc[mi][ni][3] + bsv);
        *(short4*)(v_frag + idx) = s4;
      }
    }
  }
}

// ---------------------------------------------------------------------------
// Kernel 2: flash attention v9 — R5 skeleton + fragment-major coalesced loads.
// Q frags: registers (loaded once, coalesced; q_lds deleted -> LDS 34.8 KB).
// K B-frags / V A-frags: 1KB coalesced global loads from k_frag/v_frag
// (fixes the 16-row x 64B scatter of R3-R8: 2x line amplification + 2x
// request count was the latency-product limiter).
// 512 blocks, 256 thr, XCD swizzle, fixed-max softmax, 2 barriers/sup.
// ---------------------------------------------------------------------------
__global__ __launch_bounds__(256, 2) void attn_kernel(
    const unsigned short* __restrict__ q_frag, const unsigned short* __restrict__ k_frag,
    const unsigned short* __restrict__ v_frag, unsigned short* __restrict__ o_ws) {
  __shared__ short p_lds[64][264];  // 64 q x 256 kv (132 dw/row)
  __shared__ float l_sh[4][64];

  const int tid = threadIdx.x;
  const int wid = tid >> 6, lane = tid & 63;
  const int quad = lane >> 4, l16 = lane & 15;
  const int blk = blockIdx.x;
  const int g = blk & 7;                 // XCD (dispatch round-robin heuristic)
  const int qt = (blk >> 3) & 15;        // q tile (64 rows)
  const int bh = g + 8 * (blk >> 7);     // 16 same-bh blocks share one XCD
  const size_t fbase = (size_t)bh * 262144;

  // Q fragments: wave's 16 q-rows, all 8 d-chunks — coalesced, once.
  bf8 qf[8];
  {
    const unsigned short* qp = q_frag + fbase + (size_t)(qt * 4 + wid) * 4096 + lane * 8;
#pragma unroll
    for (int kc = 0; kc < 8; kc++) qf[kc] = *(const bf8*)(qp + kc * 512);
  }

  const f4 z4 = {0.f, 0.f, 0.f, 0.f};
  f4 Oacc[4][4];  // [mi(d)][nq(q)]: d = wid*64+mi*16+quad*4+reg, q = nq*16+l16
#pragma unroll
  for (int i = 0; i < 4; i++)
#pragma unroll
    for (int j = 0; j < 4; j++) Oacc[i][j] = z4;
  float lpart[4][4];
#pragma unroll
  for (int i = 0; i < 4; i++)
#pragma unroll
    for (int j = 0; j < 4; j++) lpart[i][j] = 0.f;

  for (int sup = 0; sup < 4; sup++) {
    // ---- S = Q K^T : [64 q x 64 kv_own], K=256; K frags coalesced
    f4 Sacc[4][4];
#pragma unroll
    for (int i = 0; i < 4; i++)
#pragma unroll
      for (int j = 0; j < 4; j++) Sacc[i][j] = z4;
    const unsigned short* kp = k_frag + fbase +
        (size_t)(sup * 16 + wid * 4) * 4096 + lane * 8;
#pragma unroll
    for (int kc = 0; kc < 8; kc++) {
#pragma unroll
      for (int ni = 0; ni < 4; ni++) {
        const bf8 kb = *(const bf8*)(kp + (size_t)ni * 4096 + kc * 512);
#pragma unroll
        for (int mi = 0; mi < 4; mi++)
          Sacc[mi][ni] = __builtin_amdgcn_mfma_f32_16x16x32_bf16(qf[kc], kb, Sacc[mi][ni], 0, 0, 0);
      }
      // NOTE: qf[kc] is A for ALL mi?  No — A differs per mi (16 q rows per wave
      // covers only mi via... wave has exactly 16 q rows; mi indexes S row-tiles
      // of the BLOCK's 64 q rows. Wave owns kv, so it computes all 64 q rows:
      // A-frag per mi needed. qf holds only THIS wave's 16 rows. Fixed below.
    }
    // The loop above is replaced by the correct one (kept for clarity of diff):
    // (dead code eliminated by the compiler since Sacc is rewritten)
#pragma unroll
    for (int i = 0; i < 4; i++)
#pragma unroll
      for (int j = 0; j < 4; j++) Sacc[i][j] = z4;
    {
      const unsigned short* qpa = q_frag + fbase + (size_t)(qt * 4) * 4096 + lane * 8;
#pragma unroll
      for (int kc = 0; kc < 8; kc++) {
        bf8 aq[4];
#pragma unroll
        for (int mi = 0; mi < 4; mi++)
          aq[mi] = *(const bf8*)(qpa + (size_t)mi * 4096 + kc * 512);
#pragma unroll
        for (int ni = 0; ni < 4; ni++) {
          const bf8 kb = *(const bf8*)(kp + (size_t)ni * 4096 + kc * 512);
#pragma unroll
          for (int mi = 0; mi < 4; mi++)
            Sacc[mi][ni] = __builtin_amdgcn_mfma_f32_16x16x32_bf16(aq[mi], kb, Sacc[mi][ni], 0, 0, 0);
        }
      }
    }
    __syncthreads();  // previous sup's PV reads of p_lds complete
    // ---- exp (fixed max 0), l partials, write P
#pragma unroll
    for (int mi = 0; mi < 4; mi++)
#pragma unroll
      for (int reg = 0; reg < 4; reg++) {
        float s = 0.f;
#pragma unroll
        for (int ni = 0; ni < 4; ni++) {
          const float p = exp2f(Sacc[mi][ni][reg] * 1.44269504f);
          s += p;
          p_lds[mi * 16 + quad * 4 + reg][wid * 64 + ni * 16 + l16] = (short)f2bf(p);
        }
        lpart[mi][reg] += s;
      }
    __syncthreads();  // P visible to all waves
    // ---- O^T += V^T P^T : K=256 kv, wave-private 64-d slice; V frags coalesced
    const unsigned short* vp = v_frag + fbase +
        (size_t)(wid * 4) * 16384 + (size_t)(sup * 8) * 512 + lane * 8;
#pragma unroll
    for (int kc2 = 0; kc2 < 8; kc2++) {
      bf8 av_[4], pb[4];
#pragma unroll
      for (int mi = 0; mi < 4; mi++)
        av_[mi] = *(const bf8*)(vp + (size_t)mi * 16384 + kc2 * 512);
#pragma unroll
      for (int nq = 0; nq < 4; nq++)
        pb[nq] = *(const bf8*)(&p_lds[nq * 16 + l16][kc2 * 32 + quad * 8]);
#pragma unroll
      for (int mi = 0; mi < 4; mi++)
#pragma unroll
        for (int nq = 0; nq < 4; nq++)
          Oacc[mi][nq] = __builtin_amdgcn_mfma_f32_16x16x32_bf16(av_[mi], pb[nq], Oacc[mi][nq], 0, 0, 0);
    }
  }

  // ---- final l: reduce over 16 kv-col lanes, share across waves
#pragma unroll
  for (int mi = 0; mi < 4; mi++)
#pragma unroll
    for (int reg = 0; reg < 4; reg++) {
      float v = lpart[mi][reg];
      v += __shfl_xor(v, 1, 64);
      v += __shfl_xor(v, 2, 64);
      v += __shfl_xor(v, 4, 64);
      v += __shfl_xor(v, 8, 64);
      lpart[mi][reg] = v;
    }
  if (l16 == 0) {
#pragma unroll
    for (int mi = 0; mi < 4; mi++)
#pragma unroll
      for (int reg = 0; reg < 4; reg++)
        l_sh[wid][mi * 16 + quad * 4 + reg] = lpart[mi][reg];
  }
  __syncthreads();

  // ---- epilogue: O^T[d][q] / l(q) -> o_ws [B,S,H*256]
  const int b = bh >> 3, h = bh & 7;
#pragma unroll
  for (int nq = 0; nq < 4; nq++) {
    const int q = nq * 16 + l16;
    const float inv = 1.f / (l_sh[0][q] + l_sh[1][q] + l_sh[2][q] + l_sh[3][q]);
    const size_t base = ((size_t)b * SEQ + qt * 64 + q) * (NH * DM) + h * DM + wid * 64;
#pragma unroll
    for (int mi = 0; mi < 4; mi++) {
      short4 s4;
      s4.x = (short)f2bf(Oacc[mi][nq][0] * inv);
      s4.y = (short)f2bf(Oacc[mi][nq][1] * inv);
      s4.z = (short)f2bf(Oacc[mi][nq][2] * inv);
      s4.w = (short)f2bf(Oacc[mi][nq][3] * inv);
      *(short4*)(o_ws + base + mi * 16 + quad * 4) = s4;
    }
  }
}

// ---------------------------------------------------------------------------
// Kernel 3: output projection.  BM=32, BN=64, BK=128, grid (128,4).
// ---------------------------------------------------------------------------
__global__ __launch_bounds__(256) void outproj_kernel(
    const unsigned short* __restrict__ o_ws, const unsigned short* __restrict__ WoT,
    const float* __restrict__ bo, float* __restrict__ out) {
  __shared__ short a_lds[32][136];
  __shared__ short b_lds[64][136];

  const int tid = threadIdx.x;
  const int wid = tid >> 6, lane = tid & 63;
  const int quad = lane >> 4, l16 = lane & 15;
  const int wm = wid & 1, wn = wid >> 1;
  const int m0 = blockIdx.x * 32, n0 = blockIdx.y * 64;

  const f4 z4 = {0.f, 0.f, 0.f, 0.f};
  f4 acc[2];
#pragma unroll
  for (int i = 0; i < 2; i++) acc[i] = z4;

  const int ch = tid & 15, row = tid >> 4;
  for (int ko = 0; ko < 16; ko++) {
    const int k0 = ko * 128;
#pragma unroll
    for (int rb = 0; rb < 2; rb++) {
      int r = row + rb * 16;
      *(bf8*)(&a_lds[r][ch * 8]) = *(const bf8*)(o_ws + (size_t)(m0 + r) * 2048 + k0 + ch * 8);
    }
#pragma unroll
    for (int rb = 0; rb < 4; rb++) {
      int r = row + rb * 16;
      *(bf8*)(&b_lds[r][ch * 8]) = *(const bf8*)(WoT + (size_t)(n0 + r) * 2048 + k0 + ch * 8);
    }
    __syncthreads();
#pragma unroll
    for (int kc = 0; kc < 4; kc++) {
      const bf8 af = *(const bf8*)(&a_lds[wm * 16 + l16][kc * 32 + quad * 8]);
      bf8 bfv[2];
#pragma unroll
      for (int ni = 0; ni < 2; ni++)
        bfv[ni] = *(const bf8*)(&b_lds[wn * 32 + ni * 16 + l16][kc * 32 + quad * 8]);
#pragma unroll
      for (int ni = 0; ni < 2; ni++)
        acc[ni] = __builtin_amdgcn_mfma_f32_16x16x32_bf16(af, bfv[ni], acc[ni], 0, 0, 0);
    }
    __syncthreads();
  }
#pragma unroll
  for (int ni = 0; ni < 2; ni++) {
    const int n = n0 + wn * 32 + ni * 16 + l16;
    const float bv = bo[n];
#pragma unroll
    for (int reg = 0; reg < 4; reg++) {
      const int m = m0 + wm * 16 + quad * 4 + reg;
      out[(size_t)m * DM + n] = acc[ni][reg] + bv;
    }
  }
}

// ---------------------------------------------------------------------------
extern "C" void kernel_launch(void* const* d_in, const int* in_sizes, int n_in,
                              void* d_out, int out_size, void* d_ws, size_t ws_size,
                              hipStream_t stream) {
  const float* Q  = (const float*)d_in[0];
  const float* K  = (const float*)d_in[1];
  const float* V  = (const float*)d_in[2];
  const float* Wq = (const float*)d_in[3];
  const float* bq = (const float*)d_in[4];
  const float* Wk = (const float*)d_in[5];
  const float* bk = (const float*)d_in[6];
  const float* Wv = (const float*)d_in[7];
  const float* bv = (const float*)d_in[8];
  const float* Wo = (const float*)d_in[9];
  const float* bo = (const float*)d_in[10];
  float* out = (float*)d_out;

  char* ws = (char*)d_ws;
  const size_t QS = (size_t)NB * NH * SEQ * DM * 2;  // 16 MiB each
  unsigned short* q_frag = (unsigned short*)(ws);
  unsigned short* k_frag = (unsigned short*)(ws + QS);
  unsigned short* v_frag = (unsigned short*)(ws + 2 * QS);
  unsigned short* o_ws   = (unsigned short*)(ws + 3 * QS);
  const size_t WT = (size_t)2048 * 256 * 2;  // 1 MiB each
  unsigned short* Wt3 = (unsigned short*)(ws + 4 * QS);           // 3 MiB
  unsigned short* WoT = (unsigned short*)(ws + 4 * QS + 3 * WT);  // 1 MiB
  // Xbf (6 MiB) aliases o_ws: proj reads it before attn overwrites o_ws.
  unsigned short* Xbf = o_ws;

  prep_kernel<<<dim3(1024, 7), 256, 0, stream>>>(Wq, Wk, Wv, Wo, Q, K, V,
                                                 Wt3, WoT, Xbf);
  proj_kernel<<<dim3(32, 16, 3), 256, 0, stream>>>(Xbf, Wt3, bq, bk, bv,
                                                   q_frag, k_frag, v_frag);
  attn_kernel<<<512, 256, 0, stream>>>(q_frag, k_frag, v_frag, o_ws);
  outproj_kernel<<<dim3(128, 4), 256, 0, stream>>>(o_ws, WoT, bo, out);
}

// Round 10
// 184.266 us; speedup vs baseline: 1.1264x; 1.1264x over previous
//
#include <hip/hip_runtime.h>
#include <stdint.h>

#define NB 4      // batch
#define SEQ 1024  // sequence
#define DM 256    // d_model == head_dim
#define NH 8      // heads

typedef __attribute__((ext_vector_type(8))) short bf8;   // 8 bf16 (4 VGPRs)
typedef __attribute__((ext_vector_type(4))) float f4;    // MFMA accumulator

__device__ __forceinline__ unsigned short f2bf(float f) {
  union { float f; uint32_t u; } c; c.f = f;
  uint32_t u = c.u;
  return (unsigned short)((u + 0x7FFFu + ((u >> 16) & 1u)) >> 16); // RNE
}

// async global->LDS DMA, 16B per lane (m97 recipe): lds dst = base + lane*16.
__device__ __forceinline__ void gl_lds16(const unsigned short* g, short* l) {
  __builtin_amdgcn_global_load_lds(
      (const __attribute__((address_space(1))) unsigned int*)g,
      (__attribute__((address_space(3))) unsigned int*)l, 16, 0, 0);
}

// Fragment-major layouts (per bh slice = 262144 elems = 512 KB):
//  q_frag/k_frag: [tile16 (token/16)][dchunk (d/32)][lane64][j8]
//     element (tok = tile*16 + (lane&15), d = dchunk*32 + (lane>>4)*8 + j)
//  v_frag:        [dtile (d/16)][kvchunk (kv/32)][lane64][j8]
//     element (d = dtile*16 + (lane&15), kv = kvchunk*32 + (lane>>4)*8 + j)
// One wave fragment = lane*8 within a 512-elem block: 1KB, DMA-linear.

// ---------------------------------------------------------------------------
// Kernel 0: ALL prep in one launch.  grid (1024, 7), 256 thr.
// ---------------------------------------------------------------------------
__global__ __launch_bounds__(256) void prep_kernel(
    const float* __restrict__ Wq, const float* __restrict__ Wk,
    const float* __restrict__ Wv, const float* __restrict__ Wo,
    const float* __restrict__ Q, const float* __restrict__ K,
    const float* __restrict__ V,
    unsigned short* __restrict__ Wt3, unsigned short* __restrict__ WoT,
    unsigned short* __restrict__ Xbf) {
  const int z = blockIdx.y;
  const int tid = threadIdx.x;
  if (z >= 4) {
    const float* src = (z == 4) ? Q : (z == 5) ? K : V;
    const size_t off = (size_t)blockIdx.x * 1024 + tid * 4;
    const float4 v = *(const float4*)(src + off);
    short4 s;
    s.x = (short)f2bf(v.x); s.y = (short)f2bf(v.y);
    s.z = (short)f2bf(v.z); s.w = (short)f2bf(v.w);
    *(short4*)(Xbf + (size_t)(z - 4) * 4096 * 256 + off) = s;
    return;
  }
  if (blockIdx.x >= 512) return;
  const float* in;
  unsigned short* out;
  int R, C, bx, by;
  if (z < 3) {
    in = (z == 0) ? Wq : (z == 1) ? Wk : Wv;
    out = Wt3 + (size_t)z * 2048 * 256;
    R = 256; C = 2048; bx = blockIdx.x & 63; by = blockIdx.x >> 6;
  } else {
    in = Wo; out = WoT;
    R = 2048; C = 256; bx = blockIdx.x & 7; by = blockIdx.x >> 3;
  }
  __shared__ float t[32][33];
  const int c0 = bx * 32, r0 = by * 32;
  const int tx = tid & 31, ty = tid >> 5;
#pragma unroll
  for (int i = 0; i < 4; i++) {
    int r = r0 + ty + i * 8;
    t[ty + i * 8][tx] = in[(size_t)r * C + c0 + tx];
  }
  __syncthreads();
#pragma unroll
  for (int i = 0; i < 4; i++) {
    int c = c0 + ty + i * 8;
    out[(size_t)c * R + r0 + tx] = f2bf(t[tx][ty + i * 8]);
  }
}

// ---------------------------------------------------------------------------
// Kernel 1: QKV projection GEMM, m97-style; fragment-major epilogue (R9).
// ---------------------------------------------------------------------------
__global__ __launch_bounds__(256) void proj_kernel(
    const unsigned short* __restrict__ Xbf, const unsigned short* __restrict__ Wt3,
    const float* __restrict__ bq, const float* __restrict__ bk, const float* __restrict__ bv,
    unsigned short* __restrict__ q_frag, unsigned short* __restrict__ k_frag,
    unsigned short* __restrict__ v_frag) {
  const int z = blockIdx.z;
  const unsigned short* X = Xbf + (size_t)z * 4096 * 256;
  const unsigned short* Wt = Wt3 + (size_t)z * 2048 * 256;
  const float* bias = (z == 0) ? bq : (z == 1) ? bk : bv;

  __shared__ short a_lds[128 * 32];
  __shared__ short b_lds[128 * 32];

  const int tid = threadIdx.x;
  const int wid = tid >> 6, lane = tid & 63;
  const int quad = lane >> 4, l16 = lane & 15;
  const int wm = wid >> 1, wn = wid & 1;
  const int m0 = blockIdx.x * 128, n0 = blockIdx.y * 128;

  f4 acc[4][4];
  const f4 z4 = {0.f, 0.f, 0.f, 0.f};
#pragma unroll
  for (int i = 0; i < 4; i++)
#pragma unroll
    for (int j = 0; j < 4; j++) acc[i][j] = z4;

  const int srow = lane >> 2;
  const int schunk = lane & 3;
  const int cxor = quad ^ (l16 & 3);

  for (int ko = 0; ko < 8; ko++) {
    const int k0 = ko * 32;
#pragma unroll
    for (int j = 0; j < 2; j++) {
      const int i = wid * 2 + j;
      const int row = i * 16 + srow;
      const int sc = (schunk ^ (row & 3)) * 8;
      gl_lds16(X + (size_t)(m0 + row) * DM + k0 + sc, a_lds + i * 512);
      gl_lds16(Wt + (size_t)(n0 + row) * DM + k0 + sc, b_lds + i * 512);
    }
    __syncthreads();
    bf8 af[4], bfv[4];
#pragma unroll
    for (int mi = 0; mi < 4; mi++)
      af[mi] = *(const bf8*)(a_lds + (wm * 64 + mi * 16 + l16) * 32 + cxor * 8);
#pragma unroll
    for (int ni = 0; ni < 4; ni++)
      bfv[ni] = *(const bf8*)(b_lds + (wn * 64 + ni * 16 + l16) * 32 + cxor * 8);
#pragma unroll
    for (int mi = 0; mi < 4; mi++)
#pragma unroll
      for (int ni = 0; ni < 4; ni++)
        acc[mi][ni] = __builtin_amdgcn_mfma_f32_16x16x32_bf16(af[mi], bfv[ni], acc[mi][ni], 0, 0, 0);
    __syncthreads();
  }

  if (z < 2) {
    const float scale = (z == 0) ? 0.0625f : 1.0f;  // fold 1/sqrt(256) into q
    unsigned short* dst = (z == 0) ? q_frag : k_frag;
#pragma unroll
    for (int ni = 0; ni < 4; ni++) {
      const int n = n0 + wn * 64 + ni * 16 + l16;
      const float bsv = bias[n];
      const int h = n >> 8, d = n & 255;
      const int dpart = (d >> 5) * 512 + (16 * ((d >> 3) & 3)) * 8 + (d & 7);
#pragma unroll
      for (int mi = 0; mi < 4; mi++) {
#pragma unroll
        for (int reg = 0; reg < 4; reg++) {
          const int m = m0 + wm * 64 + mi * 16 + quad * 4 + reg;
          const int b = m >> 10, sr = m & 1023;
          const size_t idx = ((size_t)(b * NH + h) * 64 + (sr >> 4)) * 4096 +
                             dpart + (sr & 15) * 8;
          dst[idx] = f2bf((acc[mi][ni][reg] + bsv) * scale);
        }
      }
    }
  } else {
#pragma unroll
    for (int ni = 0; ni < 4; ni++) {
      const int n = n0 + wn * 64 + ni * 16 + l16;
      const float bsv = bias[n];
      const int h = n >> 8, d = n & 255;
#pragma unroll
      for (int mi = 0; mi < 4; mi++) {
        const int m = m0 + wm * 64 + mi * 16 + quad * 4;
        const int b = m >> 10, sr = m & 1023;
        const size_t idx = ((size_t)(b * NH + h) * 16 + (d >> 4)) * 16384 +
                           (size_t)(sr >> 5) * 512 +
                           ((d & 15) + 16 * ((sr >> 3) & 3)) * 8 + (sr & 7);
        short4 s4;
        s4.x = (short)f2bf(acc[mi][ni][0] + bsv);
        s4.y = (short)f2bf(acc[mi][ni][1] + bsv);
        s4.z = (short)f2bf(acc[mi][ni][2] + bsv);
        s4.w = (short)f2bf(acc[mi][ni][3] + bsv);
        *(short4*)(v_frag + idx) = s4;
      }
    }
  }
}

// ---------------------------------------------------------------------------
// Kernel 2: flash attention v10 — m97-style K staging via global_load_lds.
// The R3-R9 wall (~80 µs, all pipes <25%) = per-CU outstanding-miss capacity:
// hundreds of per-lane VMEM fragment loads. v10: K tile (kv64, 32KB) DMA'd
// to LDS (8 gl_lds16/wave, linear thanks to fragment-major layout), S-phase
// B-frags from ds_read_b128; Q in registers (wave owns q16); PV does only
// 8 direct VMEM loads/t (V A-frags).  2 barriers/t; DMA(t+1) overlaps PV(t).
// Wave roles: S-phase wave owns q16 (all kv64); PV-phase wave owns d64.
// Fixed-max softmax; l per-lane accumulate, single end reduction.
// grid 512, XCD swizzle.  LDS 41.3 KB.
// ---------------------------------------------------------------------------
__global__ __launch_bounds__(256) void attn_kernel(
    const unsigned short* __restrict__ q_frag, const unsigned short* __restrict__ k_frag,
    const unsigned short* __restrict__ v_frag, unsigned short* __restrict__ o_ws) {
  __shared__ short k_lds[16384];    // 64 kv x 256 d, fragment-major (32 KB)
  __shared__ short p_lds[64][72];   // 64 q x 64 kv (36 dw/row == 4 mod 32)
  __shared__ float l_sh[64];

  const int tid = threadIdx.x;
  const int wid = tid >> 6, lane = tid & 63;
  const int quad = lane >> 4, l16 = lane & 15;
  const int blk = blockIdx.x;
  const int g = blk & 7;                 // XCD (dispatch round-robin heuristic)
  const int qt = (blk >> 3) & 15;        // q tile (64 rows)
  const int bh = g + 8 * (blk >> 7);     // 16 same-bh blocks share one XCD
  const size_t fbase = (size_t)bh * 262144;

  // Q fragments: wave's own 16 q-rows, all 8 d-chunks (coalesced, once).
  bf8 qf[8];
  {
    const unsigned short* qp = q_frag + fbase + (size_t)(qt * 4 + wid) * 4096 + lane * 8;
#pragma unroll
    for (int kc = 0; kc < 8; kc++) qf[kc] = *(const bf8*)(qp + kc * 512);
  }

  const f4 z4 = {0.f, 0.f, 0.f, 0.f};
  f4 Oacc[4][4];  // [mi(d)][nq(q)]: d = wid*64+mi*16+quad*4+reg, q = nq*16+l16
#pragma unroll
  for (int i = 0; i < 4; i++)
#pragma unroll
    for (int j = 0; j < 4; j++) Oacc[i][j] = z4;
  float lpart[4];  // per (lane, reg): q = wid*16+quad*4+reg, partial over kv=l16-col
#pragma unroll
  for (int i = 0; i < 4; i++) lpart[i] = 0.f;

  // prologue: DMA K tile 0 (32 KB linear: k_frag[fbase + 0*16384 ..])
  {
    const unsigned short* ksrc = k_frag + fbase + (size_t)wid * 4096 + lane * 8;
#pragma unroll
    for (int jj = 0; jj < 8; jj++)
      gl_lds16(ksrc + jj * 512, k_lds + (wid * 8 + jj) * 512);
  }
  __syncthreads();

  for (int t = 0; t < 16; t++) {
    // ---- S-phase: S[16q_own x 64kv], K=256.  A=qf (regs), B from k_lds.
    f4 Sacc[4];
#pragma unroll
    for (int i = 0; i < 4; i++) Sacc[i] = z4;
#pragma unroll
    for (int kc = 0; kc < 8; kc++) {
      const bf8 aq = qf[kc];
#pragma unroll
      for (int ni = 0; ni < 4; ni++) {
        const bf8 kb = *(const bf8*)(k_lds + (ni * 8 + kc) * 512 + lane * 8);
        Sacc[ni] = __builtin_amdgcn_mfma_f32_16x16x32_bf16(aq, kb, Sacc[ni], 0, 0, 0);
      }
    }
    // ---- exp (fixed max 0), l partials, write P rows (wave owns q16 rows)
#pragma unroll
    for (int reg = 0; reg < 4; reg++) {
      const int qrow = wid * 16 + quad * 4 + reg;
      float s = 0.f;
#pragma unroll
      for (int ni = 0; ni < 4; ni++) {
        const float p = exp2f(Sacc[ni][reg] * 1.44269504f);
        s += p;
        p_lds[qrow][ni * 16 + l16] = (short)f2bf(p);
      }
      lpart[reg] += s;
    }
    __syncthreads();  // k_lds reads done; p_lds(t) visible
    // ---- DMA K(t+1) — overlaps PV compute, drained by the next barrier
    if (t < 15) {
      const unsigned short* ksrc = k_frag + fbase + (size_t)(t + 1) * 16384 +
                                   (size_t)wid * 4096 + lane * 8;
#pragma unroll
      for (int jj = 0; jj < 8; jj++)
        gl_lds16(ksrc + jj * 512, k_lds + (wid * 8 + jj) * 512);
    }
    // ---- PV: O^T[64d_own x 64q] += V^T[64d x kv64] P[kv64 x 64q]
    const unsigned short* vp = v_frag + fbase + (size_t)(wid * 4) * 16384 +
                               (size_t)(t * 2) * 512 + lane * 8;
#pragma unroll
    for (int kc2 = 0; kc2 < 2; kc2++) {
      bf8 av_[4], pb[4];
#pragma unroll
      for (int mi = 0; mi < 4; mi++)
        av_[mi] = *(const bf8*)(vp + (size_t)mi * 16384 + kc2 * 512);
#pragma unroll
      for (int nq = 0; nq < 4; nq++)
        pb[nq] = *(const bf8*)(&p_lds[nq * 16 + l16][kc2 * 32 + quad * 8]);
#pragma unroll
      for (int mi = 0; mi < 4; mi++)
#pragma unroll
        for (int nq = 0; nq < 4; nq++)
          Oacc[mi][nq] = __builtin_amdgcn_mfma_f32_16x16x32_bf16(av_[mi], pb[nq], Oacc[mi][nq], 0, 0, 0);
    }
    __syncthreads();  // p_lds consumed; K(t+1) DMA drained per-wave
  }

  // ---- final l: reduce over 16 kv-col lanes (each q owned by one wave)
#pragma unroll
  for (int reg = 0; reg < 4; reg++) {
    float v = lpart[reg];
    v += __shfl_xor(v, 1, 64);
    v += __shfl_xor(v, 2, 64);
    v += __shfl_xor(v, 4, 64);
    v += __shfl_xor(v, 8, 64);
    if (l16 == 0) l_sh[wid * 16 + quad * 4 + reg] = v;
  }
  __syncthreads();

  // ---- epilogue: O^T[d][q] / l(q) -> o_ws [B,S,H*256]
  const int b = bh >> 3, h = bh & 7;
#pragma unroll
  for (int nq = 0; nq < 4; nq++) {
    const int q = nq * 16 + l16;
    const float inv = 1.f / l_sh[q];
    const size_t base = ((size_t)b * SEQ + qt * 64 + q) * (NH * DM) + h * DM + wid * 64;
#pragma unroll
    for (int mi = 0; mi < 4; mi++) {
      short4 s4;
      s4.x = (short)f2bf(Oacc[mi][nq][0] * inv);
      s4.y = (short)f2bf(Oacc[mi][nq][1] * inv);
      s4.z = (short)f2bf(Oacc[mi][nq][2] * inv);
      s4.w = (short)f2bf(Oacc[mi][nq][3] * inv);
      *(short4*)(o_ws + base + mi * 16 + quad * 4) = s4;
    }
  }
}

// ---------------------------------------------------------------------------
// Kernel 3: output projection.  BM=32, BN=64, BK=128, grid (128,4).
// ---------------------------------------------------------------------------
__global__ __launch_bounds__(256) void outproj_kernel(
    const unsigned short* __restrict__ o_ws, const unsigned short* __restrict__ WoT,
    const float* __restrict__ bo, float* __restrict__ out) {
  __shared__ short a_lds[32][136];
  __shared__ short b_lds[64][136];

  const int tid = threadIdx.x;
  const int wid = tid >> 6, lane = tid & 63;
  const int quad = lane >> 4, l16 = lane & 15;
  const int wm = wid & 1, wn = wid >> 1;
  const int m0 = blockIdx.x * 32, n0 = blockIdx.y * 64;

  const f4 z4 = {0.f, 0.f, 0.f, 0.f};
  f4 acc[2];
#pragma unroll
  for (int i = 0; i < 2; i++) acc[i] = z4;

  const int ch = tid & 15, row = tid >> 4;
  for (int ko = 0; ko < 16; ko++) {
    const int k0 = ko * 128;
#pragma unroll
    for (int rb = 0; rb < 2; rb++) {
      int r = row + rb * 16;
      *(bf8*)(&a_lds[r][ch * 8]) = *(const bf8*)(o_ws + (size_t)(m0 + r) * 2048 + k0 + ch * 8);
    }
#pragma unroll
    for (int rb = 0; rb < 4; rb++) {
      int r = row + rb * 16;
      *(bf8*)(&b_lds[r][ch * 8]) = *(const bf8*)(WoT + (size_t)(n0 + r) * 2048 + k0 + ch * 8);
    }
    __syncthreads();
#pragma unroll
    for (int kc = 0; kc < 4; kc++) {
      const bf8 af = *(const bf8*)(&a_lds[wm * 16 + l16][kc * 32 + quad * 8]);
      bf8 bfv[2];
#pragma unroll
      for (int ni = 0; ni < 2; ni++)
        bfv[ni] = *(const bf8*)(&b_lds[wn * 32 + ni * 16 + l16][kc * 32 + quad * 8]);
#pragma unroll
      for (int ni = 0; ni < 2; ni++)
        acc[ni] = __builtin_amdgcn_mfma_f32_16x16x32_bf16(af, bfv[ni], acc[ni], 0, 0, 0);
    }
    __syncthreads();
  }
#pragma unroll
  for (int ni = 0; ni < 2; ni++) {
    const int n = n0 + wn * 32 + ni * 16 + l16;
    const float bv = bo[n];
#pragma unroll
    for (int reg = 0; reg < 4; reg++) {
      const int m = m0 + wm * 16 + quad * 4 + reg;
      out[(size_t)m * DM + n] = acc[ni][reg] + bv;
    }
  }
}

// ---------------------------------------------------------------------------
extern "C" void kernel_launch(void* const* d_in, const int* in_sizes, int n_in,
                              void* d_out, int out_size, void* d_ws, size_t ws_size,
                              hipStream_t stream) {
  const float* Q  = (const float*)d_in[0];
  const float* K  = (const float*)d_in[1];
  const float* V  = (const float*)d_in[2];
  const float* Wq = (const float*)d_in[3];
  const float* bq = (const float*)d_in[4];
  const float* Wk = (const float*)d_in[5];
  const float* bk = (const float*)d_in[6];
  const float* Wv = (const float*)d_in[7];
  const float* bv = (const float*)d_in[8];
  const float* Wo = (const float*)d_in[9];
  const float* bo = (const float*)d_in[10];
  float* out = (float*)d_out;

  char* ws = (char*)d_ws;
  const size_t QS = (size_t)NB * NH * SEQ * DM * 2;  // 16 MiB each
  unsigned short* q_frag = (unsigned short*)(ws);
  unsigned short* k_frag = (unsigned short*)(ws + QS);
  unsigned short* v_frag = (unsigned short*)(ws + 2 * QS);
  unsigned short* o_ws   = (unsigned short*)(ws + 3 * QS);
  const size_t WT = (size_t)2048 * 256 * 2;  // 1 MiB each
  unsigned short* Wt3 = (unsigned short*)(ws + 4 * QS);           // 3 MiB
  unsigned short* WoT = (unsigned short*)(ws + 4 * QS + 3 * WT);  // 1 MiB
  // Xbf (6 MiB) aliases o_ws: proj reads it before attn overwrites o_ws.
  unsigned short* Xbf = o_ws;

  prep_kernel<<<dim3(1024, 7), 256, 0, stream>>>(Wq, Wk, Wv, Wo, Q, K, V,
                                                 Wt3, WoT, Xbf);
  proj_kernel<<<dim3(32, 16, 3), 256, 0, stream>>>(Xbf, Wt3, bq, bk, bv,
                                                   q_frag, k_frag, v_frag);
  attn_kernel<<<512, 256, 0, stream>>>(q_frag, k_frag, v_frag, o_ws);
  outproj_kernel<<<dim3(128, 4), 256, 0, stream>>>(o_ws, WoT, bo, out);
}